// Round 12
// baseline (294.839 us; speedup 1.0000x reference)
//
#include <hip/hip_runtime.h>

typedef short s16x8 __attribute__((ext_vector_type(8)));
typedef float f32x4 __attribute__((ext_vector_type(4)));
typedef float f32x16 __attribute__((ext_vector_type(16)));
typedef unsigned int u32x2 __attribute__((ext_vector_type(2)));
typedef unsigned int u32x4 __attribute__((ext_vector_type(4)));

__device__ inline float bf2f(unsigned short u) {
    union { float f; unsigned int i; } x; x.i = ((unsigned int)u) << 16; return x.f;
}
__device__ inline unsigned short f2bf(float f) {
    union { float f; unsigned int i; } x; x.f = f;
    unsigned int r = x.i + 0x7fff + ((x.i >> 16) & 1);
    return (unsigned short)(r >> 16);
}
// round-half-up bf16 pair pack: low half = a, high half = b
__device__ inline unsigned int pack_bf16(float a, float b) {
    unsigned int ia = __float_as_uint(a) + 0x8000u;
    unsigned int ib = __float_as_uint(b) + 0x8000u;
    return (ia >> 16) | (ib & 0xffff0000u);
}

__device__ inline void gload_lds16(const unsigned short* g, unsigned short* l) {
    __builtin_amdgcn_global_load_lds(
        (const __attribute__((address_space(1))) unsigned int*)g,
        (__attribute__((address_space(3))) unsigned int*)l, 16, 0, 0);
}

// ---------------------------------------------------------------------------
// Input dtype probe: fp32 low-halves have ~uniform exponent bits; bf16 data
// concentrates in [117,129]. flag=1 -> inputs are fp32.
// ---------------------------------------------------------------------------
__global__ void detect_dtype(const unsigned short* __restrict__ x16, int* flag) {
    __shared__ int s[256];
    int tid = threadIdx.x;
    int cnt = 0;
    for (int i = tid; i < 4096; i += 256) {
        unsigned short u = x16[2 * i];
        int e = (u >> 7) & 0xFF;
        if (e >= 117 && e <= 129) cnt++;
    }
    s[tid] = cnt;
    __syncthreads();
    for (int off = 128; off; off >>= 1) {
        if (tid < off) s[tid] += s[tid + off];
        __syncthreads();
    }
    if (tid == 0) *flag = (s[0] < 2048) ? 1 : 0;
}

__global__ void convert_x(const void* __restrict__ in, unsigned short* __restrict__ out,
                          const int* __restrict__ flag, int n) {
    int mode = *flag;
    int i0 = (blockIdx.x * 256 + threadIdx.x) * 8;
    if (i0 >= n) return;
    if (mode) {
        const f32x4* f = (const f32x4*)in;
        f32x4 a = f[i0 >> 2];
        f32x4 c = f[(i0 >> 2) + 1];
        u32x4 o;
        o[0] = pack_bf16(a[0], a[1]);
        o[1] = pack_bf16(a[2], a[3]);
        o[2] = pack_bf16(c[0], c[1]);
        o[3] = pack_bf16(c[2], c[3]);
        *(u32x4*)(out + i0) = o;
    } else {
        *(s16x8*)(out + i0) = *(const s16x8*)((const unsigned short*)in + i0);
    }
}

__global__ void cvt_bias(const void* __restrict__ in, float* __restrict__ out,
                         const int* __restrict__ flag, int n) {
    int i = blockIdx.x * 256 + threadIdx.x;
    if (i >= n) return;
    out[i] = (*flag) ? ((const float*)in)[i] : bf2f(((const unsigned short*)in)[i]);
}

// ---------------------------------------------------------------------------
// Transpose + convert weights: (R x C) fp32/bf16 -> (C x R) bf16
// ---------------------------------------------------------------------------
__global__ void transpose_cvt(const void* __restrict__ in, unsigned short* __restrict__ out,
                              const int* __restrict__ flag, int R, int C) {
    __shared__ unsigned short t[64][72];
    int mode = *flag;
    int r0 = blockIdx.y * 64, c0 = blockIdx.x * 64;
    for (int i = threadIdx.x; i < 64 * 64; i += 256) {
        int r = i >> 6, c = i & 63;
        size_t idx = (size_t)(r0 + r) * C + (c0 + c);
        t[r][c] = mode ? f2bf(((const float*)in)[idx]) : ((const unsigned short*)in)[idx];
    }
    __syncthreads();
    for (int i = threadIdx.x; i < 64 * 64; i += 256) {
        int c = i >> 6, r = i & 63;
        out[(size_t)(c0 + c) * R + (r0 + r)] = t[r][c];
    }
}

// ---------------------------------------------------------------------------
// V transpose: qkv V region -> Vt[bh][64 d][2048 k] (bf16)
// ---------------------------------------------------------------------------
__global__ __launch_bounds__(256) void transpose_v(
    const unsigned short* __restrict__ qkv, unsigned short* __restrict__ Vt) {
    __shared__ unsigned short t[64][72];
    int bh = blockIdx.y; int b = bh >> 4, h = bh & 15;
    int k0 = blockIdx.x * 64;
    int tid = threadIdx.x;
    int kr = tid >> 2, db = (tid & 3) * 16;
    const unsigned short* src = qkv + ((size_t)(k0 + kr) * 4 + b) * 3072 + 2048 + h * 64 + db;
    *(s16x8*)&t[kr][db] = *(const s16x8*)src;
    *(s16x8*)&t[kr][db + 8] = *(const s16x8*)(src + 8);
    __syncthreads();
    int d = tid >> 2, kb = (tid & 3) * 16;
    unsigned short* dst = Vt + (size_t)bh * 131072 + (size_t)d * 2048 + k0 + kb;
    s16x8 a, c;
#pragma unroll
    for (int j = 0; j < 8; ++j) a[j] = t[kb + j][d];
#pragma unroll
    for (int j = 0; j < 8; ++j) c[j] = t[kb + 8 + j][d];
    *(s16x8*)dst = a;
    *(s16x8*)(dst + 8) = c;
}

// ---------------------------------------------------------------------------
// Pipelined GEMM: C = A * BT^T + bias. BM=256, BN=128, BK=64, 512 thr = 8
// waves (4M x 2N). Triple-buffered LDS (144KB), prefetch distance 2,
// counted s_waitcnt vmcnt(6) (never vmcnt(0) mid-loop). XOR LDS layout.
// ---------------------------------------------------------------------------
__global__ __launch_bounds__(512) void gemm_pipe_kernel(
    const unsigned short* __restrict__ A, const unsigned short* __restrict__ BT,
    const float* __restrict__ bias, void* __restrict__ Cout,
    int M, int N, int K, int qcols, float qscale, const int* __restrict__ outf32flag) {
    __shared__ unsigned short As[3][256 * 64];  // 3 x 32KB
    __shared__ unsigned short Bs[3][128 * 64];  // 3 x 16KB
    int tid = threadIdx.x;
    int lane = tid & 63, w = tid >> 6;
    int wr = w >> 1, wc = w & 1;
    int g = lane >> 4, qh = lane & 15;
    int m0 = blockIdx.y * 256, n0 = blockIdx.x * 128;
    int vxor = (lane & 7) ^ (lane >> 3);
    int axor = qh & 7;

    f32x4 z = {0.f, 0.f, 0.f, 0.f};
    f32x4 acc[4][4];
#pragma unroll
    for (int m = 0; m < 4; ++m)
#pragma unroll
        for (int n = 0; n < 4; ++n) acc[m][n] = z;

    const unsigned short* Asrc = A + (size_t)(m0 + w * 8 + (lane >> 3)) * K + vxor * 8;
    const unsigned short* Bsrc = BT + (size_t)(n0 + w * 8 + (lane >> 3)) * K + vxor * 8;

#define STAGE_A(buf, t, j) gload_lds16(Asrc + (size_t)(j) * 64 * K + (size_t)(t) * 64, \
                                       &As[buf][0] + (j) * 4096 + w * 512)
#define STAGE_B(buf, t, j) gload_lds16(Bsrc + (size_t)(j) * 64 * K + (size_t)(t) * 64, \
                                       &Bs[buf][0] + (j) * 4096 + w * 512)

    int NT = K >> 6;
    STAGE_A(0, 0, 0); STAGE_A(0, 0, 1); STAGE_A(0, 0, 2); STAGE_A(0, 0, 3);
    STAGE_B(0, 0, 0); STAGE_B(0, 0, 1);
    STAGE_A(1, 1, 0); STAGE_A(1, 1, 1); STAGE_A(1, 1, 2); STAGE_A(1, 1, 3);
    STAGE_B(1, 1, 0); STAGE_B(1, 1, 1);
    asm volatile("s_waitcnt vmcnt(6)" ::: "memory");
    __builtin_amdgcn_s_barrier();

    int cur = 0;
    for (int t = 0; t < NT; ++t) {
        int nx = cur + 2; if (nx >= 3) nx -= 3;
        bool pf = (t + 2) < NT;
        const unsigned short* Ab = &As[cur][0];
        const unsigned short* Bb = &Bs[cur][0];

        s16x8 bf[4][2];
#pragma unroll
        for (int n = 0; n < 4; ++n)
#pragma unroll
            for (int kk = 0; kk < 2; ++kk)
                bf[n][kk] = *(const s16x8*)(Bb + (size_t)(wc * 64 + n * 16 + qh) * 64 +
                                            (((kk * 4 + g) ^ axor) * 8));

        if (pf) { STAGE_A(nx, t + 2, 0); STAGE_A(nx, t + 2, 1); STAGE_B(nx, t + 2, 0); }
        {
            s16x8 af[2][2];
#pragma unroll
            for (int i = 0; i < 2; ++i)
#pragma unroll
                for (int kk = 0; kk < 2; ++kk)
                    af[i][kk] = *(const s16x8*)(Ab + (size_t)(wr * 64 + i * 16 + qh) * 64 +
                                                (((kk * 4 + g) ^ axor) * 8));
            __builtin_amdgcn_s_setprio(1);
#pragma unroll
            for (int kk = 0; kk < 2; ++kk)
#pragma unroll
                for (int i = 0; i < 2; ++i)
#pragma unroll
                    for (int n = 0; n < 4; ++n)
                        acc[i][n] = __builtin_amdgcn_mfma_f32_16x16x32_bf16(af[i][kk], bf[n][kk], acc[i][n], 0, 0, 0);
            __builtin_amdgcn_s_setprio(0);
        }
        __builtin_amdgcn_s_barrier();

        if (pf) { STAGE_A(nx, t + 2, 2); STAGE_A(nx, t + 2, 3); STAGE_B(nx, t + 2, 1); }
        {
            s16x8 af[2][2];
#pragma unroll
            for (int i = 0; i < 2; ++i)
#pragma unroll
                for (int kk = 0; kk < 2; ++kk)
                    af[i][kk] = *(const s16x8*)(Ab + (size_t)(wr * 64 + (i + 2) * 16 + qh) * 64 +
                                                (((kk * 4 + g) ^ axor) * 8));
            __builtin_amdgcn_s_setprio(1);
#pragma unroll
            for (int kk = 0; kk < 2; ++kk)
#pragma unroll
                for (int i = 0; i < 2; ++i)
#pragma unroll
                    for (int n = 0; n < 4; ++n)
                        acc[i + 2][n] = __builtin_amdgcn_mfma_f32_16x16x32_bf16(af[i][kk], bf[n][kk], acc[i + 2][n], 0, 0, 0);
            __builtin_amdgcn_s_setprio(0);
        }
        if (t + 1 < NT) {
            if (pf) asm volatile("s_waitcnt vmcnt(6)" ::: "memory");
            else    asm volatile("s_waitcnt vmcnt(0)" ::: "memory");
            __builtin_amdgcn_s_barrier();
        }
        cur = cur + 1; if (cur >= 3) cur -= 3;
    }
#undef STAGE_A
#undef STAGE_B

    bool f32out = (outf32flag != nullptr) && (*outf32flag != 0);
    int crow0 = m0 + wr * 64;
    int ccol0 = n0 + wc * 64;
#pragma unroll
    for (int n = 0; n < 4; ++n) {
        int col = ccol0 + n * 16 + qh;
        float bv = bias[col];
        float qs = (col < qcols) ? qscale : 1.0f;
#pragma unroll
        for (int m = 0; m < 4; ++m) {
            int rbase = crow0 + m * 16 + g * 4;
#pragma unroll
            for (int qq = 0; qq < 4; ++qq) {
                float v = (acc[m][n][qq] + bv) * qs;
                if (f32out)
                    ((float*)Cout)[(size_t)(rbase + qq) * N + col] = v;
                else
                    ((unsigned short*)Cout)[(size_t)(rbase + qq) * N + col] = f2bf(v);
            }
        }
    }
}

// ---------------------------------------------------------------------------
// Flash attention, 32x32x16 MFMA, swapped operands, exp2 domain, P fully
// in-register via permlane32_swap. Block: one (b,h), 256 q-rows =
// 4 waves x 2 sequential subtiles x 32. KV tiles of 64. Staging + barriers
// amortize over 2x q-rows vs round-11.
// Layout (verified R11): S^T = mfma32(Kfrag, Qfrag), lane owns col q=lane&31,
// k-row = (reg&3)+8*(reg>>2)+4*(lane>>5). PV B-frag via
// permlane32_swap(A,B) -> [0]={A.lo,B.lo}, [1]={A.hi,B.hi}.
// ---------------------------------------------------------------------------
__global__ __launch_bounds__(256) void attn_kernel(
    const unsigned short* __restrict__ qkv, const unsigned short* __restrict__ Vt,
    unsigned short* __restrict__ O) {
    int bh = blockIdx.y;
    int b = bh >> 4, h = bh & 15;
    int q0 = blockIdx.x * 256;
    int tid = threadIdx.x, lane = tid & 63, w = tid >> 6;
    int l31 = lane & 31, l5 = lane >> 5;

    __shared__ unsigned short Ks[8 * 64 * 8];   // [gd=d/8][k][8]  8KB
    __shared__ unsigned short Vs[64 * 64];      // [d][kb^(d&7)]   8KB

    // Q B-frags for both subtiles: row = q0 + w*64 + sub*32 + l31
    int qrow0 = q0 + w * 64 + l31;
    s16x8 qf[2][4];
#pragma unroll
    for (int sub = 0; sub < 2; ++sub) {
        const unsigned short* qp = qkv + ((size_t)(qrow0 + sub * 32) * 4 + b) * 3072 + h * 64 + l5 * 8;
#pragma unroll
        for (int st = 0; st < 4; ++st) qf[sub][st] = *(const s16x8*)(qp + st * 16);
    }

    f32x16 z16 = {0.f,0.f,0.f,0.f,0.f,0.f,0.f,0.f,0.f,0.f,0.f,0.f,0.f,0.f,0.f,0.f};
    f32x16 oacc[2][2];
    oacc[0][0] = z16; oacc[0][1] = z16; oacc[1][0] = z16; oacc[1][1] = z16;
    float lrun[2] = {0.f, 0.f};

    int vxor = (lane & 7) ^ (lane >> 3);

    for (int k0 = 0; k0 < 2048; k0 += 64) {
        __syncthreads();
        // stage K tile: Ks[gd][k][e] = K[k0+k][gd*8+e]
        {
            const unsigned short* ksrc = qkv + ((size_t)(k0 + lane) * 4 + b) * 3072 + 1024 + h * 64;
            gload_lds16(ksrc + w * 8, Ks + (size_t)w * 512);
            gload_lds16(ksrc + (w + 4) * 8, Ks + (size_t)(w + 4) * 512);
        }
        // stage V^T tile, inverse-swizzled source, linear LDS dest:
        // Vs[d][blk][j] = V^T[d][k0 + (blk^(d&7))*8 + j]
#pragma unroll
        for (int c = 0; c < 2; ++c) {
            int d = (c * 4 + w) * 8 + (lane >> 3);
            const unsigned short* vsrc = Vt + (size_t)bh * 131072 + (size_t)d * 2048 + k0 + vxor * 8;
            gload_lds16(vsrc, Vs + (size_t)(c * 4 + w) * 512);
        }
        __syncthreads();

#pragma unroll
        for (int sub = 0; sub < 2; ++sub) {
            // ---- S^T[k][q] (log2 domain)
            f32x16 sc[2];
            sc[0] = z16; sc[1] = z16;
#pragma unroll
            for (int st = 0; st < 4; ++st) {
                int gd = st * 2 + l5;
#pragma unroll
                for (int kt = 0; kt < 2; ++kt) {
                    s16x8 kf = *(const s16x8*)(Ks + ((size_t)(gd * 64 + kt * 32 + l31)) * 8);
                    sc[kt] = __builtin_amdgcn_mfma_f32_32x32x16_bf16(kf, qf[sub][st], sc[kt], 0, 0, 0);
                }
            }

            // ---- P = exp2(S) raw; PV B-frags in-register; PV accumulate
            float rsum = 0.f;
#pragma unroll
            for (int kt = 0; kt < 2; ++kt) {
                float p[16];
#pragma unroll
                for (int r = 0; r < 16; ++r) {
                    p[r] = __builtin_amdgcn_exp2f(sc[kt][r]);
                    rsum += p[r];
                }
#pragma unroll
                for (int ks1 = 0; ks1 < 2; ++ks1) {
                    unsigned int A0 = pack_bf16(p[8 * ks1 + 0], p[8 * ks1 + 1]);
                    unsigned int A1 = pack_bf16(p[8 * ks1 + 2], p[8 * ks1 + 3]);
                    unsigned int B0 = pack_bf16(p[8 * ks1 + 4], p[8 * ks1 + 5]);
                    unsigned int B1 = pack_bf16(p[8 * ks1 + 6], p[8 * ks1 + 7]);
                    u32x2 r0 = __builtin_amdgcn_permlane32_swap(A0, B0, false, false);
                    u32x2 r1 = __builtin_amdgcn_permlane32_swap(A1, B1, false, false);
                    union { unsigned int u[4]; s16x8 v; } uu;
                    uu.u[0] = r0[0];  // j0,1
                    uu.u[1] = r1[0];  // j2,3
                    uu.u[2] = r0[1];  // j4,5
                    uu.u[3] = r1[1];  // j6,7
                    int ks = kt * 2 + ks1;
#pragma unroll
                    for (int dt = 0; dt < 2; ++dt) {
                        int d = dt * 32 + l31;
                        int kb = (ks * 2 + l5) ^ (d & 7);
                        s16x8 vf = *(const s16x8*)(Vs + (size_t)d * 64 + kb * 8);
                        oacc[sub][dt] = __builtin_amdgcn_mfma_f32_32x32x16_bf16(vf, uu.v, oacc[sub][dt], 0, 0, 0);
                    }
                }
            }
            rsum += __shfl_xor(rsum, 32);
            lrun[sub] += rsum;
        }
    }

    // ---- epilogue: O[s][h*64 + d], d = dt*32 + (r&3) + 8*(r>>2) + 4*l5
#pragma unroll
    for (int sub = 0; sub < 2; ++sub) {
        float rl = 1.f / lrun[sub];
        unsigned short* orow = O + ((size_t)(qrow0 + sub * 32) * 4 + b) * 1024 + h * 64 + l5 * 4;
#pragma unroll
        for (int dt = 0; dt < 2; ++dt) {
#pragma unroll
            for (int g2 = 0; g2 < 4; ++g2) {
                u32x2 pv;
                pv[0] = pack_bf16(oacc[sub][dt][4 * g2 + 0] * rl, oacc[sub][dt][4 * g2 + 1] * rl);
                pv[1] = pack_bf16(oacc[sub][dt][4 * g2 + 2] * rl, oacc[sub][dt][4 * g2 + 3] * rl);
                *(u32x2*)(orow + dt * 32 + g2 * 8) = pv;
            }
        }
    }
}

// ---------------------------------------------------------------------------
extern "C" void kernel_launch(void* const* d_in, const int* in_sizes, int n_in,
                              void* d_out, int out_size, void* d_ws, size_t ws_size,
                              hipStream_t stream) {
    const void* x    = d_in[0];
    const void* Wqkv = d_in[1];
    const void* bqkv = d_in[2];
    const void* Wout = d_in[3];
    const void* bout = d_in[4];

    char* ws = (char*)d_ws;
    unsigned short* qkv   = (unsigned short*)(ws);              // 48MB
    unsigned short* Obuf  = (unsigned short*)(ws + 50331648);   // 16MB
    unsigned short* WqkvT = (unsigned short*)(ws + 67108864);   // 6MB
    unsigned short* WoutT = (unsigned short*)(ws + 73400320);   // 2MB
    unsigned short* xb    = (unsigned short*)(ws + 75497472);   // 16MB (reused as Vt)
    unsigned short* Vtg   = xb;                                 // alias: xb dead after GEMM1
    float*          bq_f  = (float*)(ws + 92274688);
    float*          bo_f  = (float*)(ws + 92286976);
    int*            flag  = (int*)(ws + 92291072);

    detect_dtype<<<1, 256, 0, stream>>>((const unsigned short*)x, flag);
    convert_x<<<4096, 256, 0, stream>>>(x, xb, flag, 8388608);
    cvt_bias<<<12, 256, 0, stream>>>(bqkv, bq_f, flag, 3072);
    cvt_bias<<<4, 256, 0, stream>>>(bout, bo_f, flag, 1024);
    transpose_cvt<<<dim3(48, 16), 256, 0, stream>>>(Wqkv, WqkvT, flag, 1024, 3072);
    transpose_cvt<<<dim3(16, 16), 256, 0, stream>>>(Wout, WoutT, flag, 1024, 1024);

    // Q prescale = 0.125 * log2(e) -> attention works in exp2 domain
    gemm_pipe_kernel<<<dim3(24, 32), 512, 0, stream>>>(xb, WqkvT, bq_f, qkv,
                                                       8192, 3072, 1024, 1024, 0.18033688f, nullptr);
    transpose_v<<<dim3(32, 64), 256, 0, stream>>>(qkv, Vtg);
    attn_kernel<<<dim3(8, 64), 256, 0, stream>>>(qkv, Vtg, Obuf);
    gemm_pipe_kernel<<<dim3(8, 32), 512, 0, stream>>>(Obuf, WoutT, bo_f, d_out,
                                                      8192, 1024, 1024, 0, 1.0f, flag);
}

// Round 13
// 285.277 us; speedup vs baseline: 1.0335x; 1.0335x over previous
//
#include <hip/hip_runtime.h>

typedef short s16x8 __attribute__((ext_vector_type(8)));
typedef float f32x4 __attribute__((ext_vector_type(4)));
typedef float f32x16 __attribute__((ext_vector_type(16)));
typedef unsigned int u32x2 __attribute__((ext_vector_type(2)));
typedef unsigned int u32x4 __attribute__((ext_vector_type(4)));

__device__ inline float bf2f(unsigned short u) {
    union { float f; unsigned int i; } x; x.i = ((unsigned int)u) << 16; return x.f;
}
__device__ inline unsigned short f2bf(float f) {
    union { float f; unsigned int i; } x; x.f = f;
    unsigned int r = x.i + 0x7fff + ((x.i >> 16) & 1);
    return (unsigned short)(r >> 16);
}
// round-half-up bf16 pair pack: low half = a, high half = b
__device__ inline unsigned int pack_bf16(float a, float b) {
    unsigned int ia = __float_as_uint(a) + 0x8000u;
    unsigned int ib = __float_as_uint(b) + 0x8000u;
    return (ia >> 16) | (ib & 0xffff0000u);
}

__device__ inline void gload_lds16(const unsigned short* g, unsigned short* l) {
    __builtin_amdgcn_global_load_lds(
        (const __attribute__((address_space(1))) unsigned int*)g,
        (__attribute__((address_space(3))) unsigned int*)l, 16, 0, 0);
}

// ---------------------------------------------------------------------------
// Input dtype probe: fp32 low-halves have ~uniform exponent bits; bf16 data
// concentrates in [117,129]. flag=1 -> inputs are fp32.
// ---------------------------------------------------------------------------
__global__ void detect_dtype(const unsigned short* __restrict__ x16, int* flag) {
    __shared__ int s[256];
    int tid = threadIdx.x;
    int cnt = 0;
    for (int i = tid; i < 4096; i += 256) {
        unsigned short u = x16[2 * i];
        int e = (u >> 7) & 0xFF;
        if (e >= 117 && e <= 129) cnt++;
    }
    s[tid] = cnt;
    __syncthreads();
    for (int off = 128; off; off >>= 1) {
        if (tid < off) s[tid] += s[tid + off];
        __syncthreads();
    }
    if (tid == 0) *flag = (s[0] < 2048) ? 1 : 0;
}

__global__ void convert_x(const void* __restrict__ in, unsigned short* __restrict__ out,
                          const int* __restrict__ flag, int n) {
    int mode = *flag;
    int i0 = (blockIdx.x * 256 + threadIdx.x) * 8;
    if (i0 >= n) return;
    if (mode) {
        const f32x4* f = (const f32x4*)in;
        f32x4 a = f[i0 >> 2];
        f32x4 c = f[(i0 >> 2) + 1];
        u32x4 o;
        o[0] = pack_bf16(a[0], a[1]);
        o[1] = pack_bf16(a[2], a[3]);
        o[2] = pack_bf16(c[0], c[1]);
        o[3] = pack_bf16(c[2], c[3]);
        *(u32x4*)(out + i0) = o;
    } else {
        *(s16x8*)(out + i0) = *(const s16x8*)((const unsigned short*)in + i0);
    }
}

__global__ void cvt_bias(const void* __restrict__ in, float* __restrict__ out,
                         const int* __restrict__ flag, int n) {
    int i = blockIdx.x * 256 + threadIdx.x;
    if (i >= n) return;
    out[i] = (*flag) ? ((const float*)in)[i] : bf2f(((const unsigned short*)in)[i]);
}

// ---------------------------------------------------------------------------
// Transpose + convert weights: (R x C) fp32/bf16 -> (C x R) bf16
// ---------------------------------------------------------------------------
__global__ void transpose_cvt(const void* __restrict__ in, unsigned short* __restrict__ out,
                              const int* __restrict__ flag, int R, int C) {
    __shared__ unsigned short t[64][72];
    int mode = *flag;
    int r0 = blockIdx.y * 64, c0 = blockIdx.x * 64;
    for (int i = threadIdx.x; i < 64 * 64; i += 256) {
        int r = i >> 6, c = i & 63;
        size_t idx = (size_t)(r0 + r) * C + (c0 + c);
        t[r][c] = mode ? f2bf(((const float*)in)[idx]) : ((const unsigned short*)in)[idx];
    }
    __syncthreads();
    for (int i = threadIdx.x; i < 64 * 64; i += 256) {
        int c = i >> 6, r = i & 63;
        out[(size_t)(c0 + c) * R + (r0 + r)] = t[r][c];
    }
}

// ---------------------------------------------------------------------------
// V transpose: qkv V region -> Vt[bh][64 d][2048 k] (bf16)
// ---------------------------------------------------------------------------
__global__ __launch_bounds__(256) void transpose_v(
    const unsigned short* __restrict__ qkv, unsigned short* __restrict__ Vt) {
    __shared__ unsigned short t[64][72];
    int bh = blockIdx.y; int b = bh >> 4, h = bh & 15;
    int k0 = blockIdx.x * 64;
    int tid = threadIdx.x;
    int kr = tid >> 2, db = (tid & 3) * 16;
    const unsigned short* src = qkv + ((size_t)(k0 + kr) * 4 + b) * 3072 + 2048 + h * 64 + db;
    *(s16x8*)&t[kr][db] = *(const s16x8*)src;
    *(s16x8*)&t[kr][db + 8] = *(const s16x8*)(src + 8);
    __syncthreads();
    int d = tid >> 2, kb = (tid & 3) * 16;
    unsigned short* dst = Vt + (size_t)bh * 131072 + (size_t)d * 2048 + k0 + kb;
    s16x8 a, c;
#pragma unroll
    for (int j = 0; j < 8; ++j) a[j] = t[kb + j][d];
#pragma unroll
    for (int j = 0; j < 8; ++j) c[j] = t[kb + 8 + j][d];
    *(s16x8*)dst = a;
    *(s16x8*)(dst + 8) = c;
}

// ---------------------------------------------------------------------------
// Pipelined GEMM: C = A * BT^T + bias. BM=256, BN=128, BK=64, 512 thr = 8
// waves (4M x 2N). Triple-buffered LDS (144KB), prefetch distance 2,
// counted s_waitcnt vmcnt(6) (never vmcnt(0) mid-loop). XOR LDS layout.
// ---------------------------------------------------------------------------
__global__ __launch_bounds__(512) void gemm_pipe_kernel(
    const unsigned short* __restrict__ A, const unsigned short* __restrict__ BT,
    const float* __restrict__ bias, void* __restrict__ Cout,
    int M, int N, int K, int qcols, float qscale, const int* __restrict__ outf32flag) {
    __shared__ unsigned short As[3][256 * 64];  // 3 x 32KB
    __shared__ unsigned short Bs[3][128 * 64];  // 3 x 16KB
    int tid = threadIdx.x;
    int lane = tid & 63, w = tid >> 6;
    int wr = w >> 1, wc = w & 1;
    int g = lane >> 4, qh = lane & 15;
    int m0 = blockIdx.y * 256, n0 = blockIdx.x * 128;
    int vxor = (lane & 7) ^ (lane >> 3);
    int axor = qh & 7;

    f32x4 z = {0.f, 0.f, 0.f, 0.f};
    f32x4 acc[4][4];
#pragma unroll
    for (int m = 0; m < 4; ++m)
#pragma unroll
        for (int n = 0; n < 4; ++n) acc[m][n] = z;

    const unsigned short* Asrc = A + (size_t)(m0 + w * 8 + (lane >> 3)) * K + vxor * 8;
    const unsigned short* Bsrc = BT + (size_t)(n0 + w * 8 + (lane >> 3)) * K + vxor * 8;

#define STAGE_A(buf, t, j) gload_lds16(Asrc + (size_t)(j) * 64 * K + (size_t)(t) * 64, \
                                       &As[buf][0] + (j) * 4096 + w * 512)
#define STAGE_B(buf, t, j) gload_lds16(Bsrc + (size_t)(j) * 64 * K + (size_t)(t) * 64, \
                                       &Bs[buf][0] + (j) * 4096 + w * 512)

    int NT = K >> 6;
    STAGE_A(0, 0, 0); STAGE_A(0, 0, 1); STAGE_A(0, 0, 2); STAGE_A(0, 0, 3);
    STAGE_B(0, 0, 0); STAGE_B(0, 0, 1);
    STAGE_A(1, 1, 0); STAGE_A(1, 1, 1); STAGE_A(1, 1, 2); STAGE_A(1, 1, 3);
    STAGE_B(1, 1, 0); STAGE_B(1, 1, 1);
    asm volatile("s_waitcnt vmcnt(6)" ::: "memory");
    __builtin_amdgcn_s_barrier();

    int cur = 0;
    for (int t = 0; t < NT; ++t) {
        int nx = cur + 2; if (nx >= 3) nx -= 3;
        bool pf = (t + 2) < NT;
        const unsigned short* Ab = &As[cur][0];
        const unsigned short* Bb = &Bs[cur][0];

        s16x8 bf[4][2];
#pragma unroll
        for (int n = 0; n < 4; ++n)
#pragma unroll
            for (int kk = 0; kk < 2; ++kk)
                bf[n][kk] = *(const s16x8*)(Bb + (size_t)(wc * 64 + n * 16 + qh) * 64 +
                                            (((kk * 4 + g) ^ axor) * 8));

        if (pf) { STAGE_A(nx, t + 2, 0); STAGE_A(nx, t + 2, 1); STAGE_B(nx, t + 2, 0); }
        {
            s16x8 af[2][2];
#pragma unroll
            for (int i = 0; i < 2; ++i)
#pragma unroll
                for (int kk = 0; kk < 2; ++kk)
                    af[i][kk] = *(const s16x8*)(Ab + (size_t)(wr * 64 + i * 16 + qh) * 64 +
                                                (((kk * 4 + g) ^ axor) * 8));
            __builtin_amdgcn_s_setprio(1);
#pragma unroll
            for (int kk = 0; kk < 2; ++kk)
#pragma unroll
                for (int i = 0; i < 2; ++i)
#pragma unroll
                    for (int n = 0; n < 4; ++n)
                        acc[i][n] = __builtin_amdgcn_mfma_f32_16x16x32_bf16(af[i][kk], bf[n][kk], acc[i][n], 0, 0, 0);
            __builtin_amdgcn_s_setprio(0);
        }
        __builtin_amdgcn_s_barrier();

        if (pf) { STAGE_A(nx, t + 2, 2); STAGE_A(nx, t + 2, 3); STAGE_B(nx, t + 2, 1); }
        {
            s16x8 af[2][2];
#pragma unroll
            for (int i = 0; i < 2; ++i)
#pragma unroll
                for (int kk = 0; kk < 2; ++kk)
                    af[i][kk] = *(const s16x8*)(Ab + (size_t)(wr * 64 + (i + 2) * 16 + qh) * 64 +
                                                (((kk * 4 + g) ^ axor) * 8));
            __builtin_amdgcn_s_setprio(1);
#pragma unroll
            for (int kk = 0; kk < 2; ++kk)
#pragma unroll
                for (int i = 0; i < 2; ++i)
#pragma unroll
                    for (int n = 0; n < 4; ++n)
                        acc[i + 2][n] = __builtin_amdgcn_mfma_f32_16x16x32_bf16(af[i][kk], bf[n][kk], acc[i + 2][n], 0, 0, 0);
            __builtin_amdgcn_s_setprio(0);
        }
        if (t + 1 < NT) {
            if (pf) asm volatile("s_waitcnt vmcnt(6)" ::: "memory");
            else    asm volatile("s_waitcnt vmcnt(0)" ::: "memory");
            __builtin_amdgcn_s_barrier();
        }
        cur = cur + 1; if (cur >= 3) cur -= 3;
    }
#undef STAGE_A
#undef STAGE_B

    bool f32out = (outf32flag != nullptr) && (*outf32flag != 0);
    int crow0 = m0 + wr * 64;
    int ccol0 = n0 + wc * 64;
#pragma unroll
    for (int n = 0; n < 4; ++n) {
        int col = ccol0 + n * 16 + qh;
        float bv = bias[col];
        float qs = (col < qcols) ? qscale : 1.0f;
#pragma unroll
        for (int m = 0; m < 4; ++m) {
            int rbase = crow0 + m * 16 + g * 4;
#pragma unroll
            for (int qq = 0; qq < 4; ++qq) {
                float v = (acc[m][n][qq] + bv) * qs;
                if (f32out)
                    ((float*)Cout)[(size_t)(rbase + qq) * N + col] = v;
                else
                    ((unsigned short*)Cout)[(size_t)(rbase + qq) * N + col] = f2bf(v);
            }
        }
    }
}

// ---------------------------------------------------------------------------
// Flash attention, 32x32x16 MFMA, swapped operands, exp2 domain, P fully
// in-register via permlane32_swap. R11 geometry (128 q-rows = 4 waves x 32,
// VGPR-lean) + double-buffered K/V staging: issue tile t+1's DMA before
// compute(t), one vmcnt(0)+barrier per tile (T3 2-phase).
// Layout (verified R11): S^T = mfma32(Kfrag, Qfrag), lane owns col q=lane&31,
// k-row = (reg&3)+8*(reg>>2)+4*(lane>>5). PV B-frag via
// permlane32_swap(A,B) -> [0]={A.lo,B.lo}, [1]={A.hi,B.hi}.
// ---------------------------------------------------------------------------
__global__ __launch_bounds__(256) void attn_kernel(
    const unsigned short* __restrict__ qkv, const unsigned short* __restrict__ Vt,
    unsigned short* __restrict__ O) {
    int bh = blockIdx.y;
    int b = bh >> 4, h = bh & 15;
    int q0 = blockIdx.x * 128;
    int tid = threadIdx.x, lane = tid & 63, w = tid >> 6;
    int l31 = lane & 31, l5 = lane >> 5;

    __shared__ unsigned short Ks[2][8 * 64 * 8];   // 16KB
    __shared__ unsigned short Vs[2][64 * 64];      // 16KB

    // Q B-frags: step st: k-chunk d = st*16 + l5*8 + j; col = q0 + w*32 + l31
    int qrow = q0 + w * 32 + l31;
    const unsigned short* qp = qkv + ((size_t)qrow * 4 + b) * 3072 + h * 64 + l5 * 8;
    s16x8 qf[4];
#pragma unroll
    for (int st = 0; st < 4; ++st) qf[st] = *(const s16x8*)(qp + st * 16);

    f32x16 z16 = {0.f,0.f,0.f,0.f,0.f,0.f,0.f,0.f,0.f,0.f,0.f,0.f,0.f,0.f,0.f,0.f};
    f32x16 oacc[2];
    oacc[0] = z16; oacc[1] = z16;
    float lrun = 0.f;

    int vxor = (lane & 7) ^ (lane >> 3);

    // 4 global_load_lds per wave per tile (2 K + 2 V)
    auto stage = [&](int buf, int k0) {
        const unsigned short* ksrc = qkv + ((size_t)(k0 + lane) * 4 + b) * 3072 + 1024 + h * 64;
        gload_lds16(ksrc + w * 8, &Ks[buf][0] + (size_t)w * 512);
        gload_lds16(ksrc + (w + 4) * 8, &Ks[buf][0] + (size_t)(w + 4) * 512);
#pragma unroll
        for (int c = 0; c < 2; ++c) {
            int d = (c * 4 + w) * 8 + (lane >> 3);
            const unsigned short* vsrc = Vt + (size_t)bh * 131072 + (size_t)d * 2048 + k0 + vxor * 8;
            gload_lds16(vsrc, &Vs[buf][0] + (size_t)(c * 4 + w) * 512);
        }
    };

    stage(0, 0);
    asm volatile("s_waitcnt vmcnt(0)" ::: "memory");  // tile 0 + Q-frags landed
    __builtin_amdgcn_s_barrier();

    for (int t = 0; t < 32; ++t) {
        int cur = t & 1;
        // issue next tile's DMA; it flies under this tile's compute.
        // buf cur^1 was last read in iter t-1, whose end-barrier has passed.
        if (t + 1 < 32) stage(cur ^ 1, (t + 1) * 64);

        // ---- S^T[k][q] (log2 domain): sc[kt], k = kt*32 + (r&3)+8*(r>>2)+4*l5
        f32x16 sc[2];
        sc[0] = z16; sc[1] = z16;
#pragma unroll
        for (int st = 0; st < 4; ++st) {
            int gd = st * 2 + l5;
#pragma unroll
            for (int kt = 0; kt < 2; ++kt) {
                s16x8 kf = *(const s16x8*)(&Ks[cur][0] + ((size_t)(gd * 64 + kt * 32 + l31)) * 8);
                sc[kt] = __builtin_amdgcn_mfma_f32_32x32x16_bf16(kf, qf[st], sc[kt], 0, 0, 0);
            }
        }

        // ---- P = exp2(S) raw; PV B-frags in-register; PV accumulate
        float rsum = 0.f;
#pragma unroll
        for (int kt = 0; kt < 2; ++kt) {
            float p[16];
#pragma unroll
            for (int r = 0; r < 16; ++r) {
                p[r] = __builtin_amdgcn_exp2f(sc[kt][r]);
                rsum += p[r];
            }
#pragma unroll
            for (int ks1 = 0; ks1 < 2; ++ks1) {
                unsigned int A0 = pack_bf16(p[8 * ks1 + 0], p[8 * ks1 + 1]);
                unsigned int A1 = pack_bf16(p[8 * ks1 + 2], p[8 * ks1 + 3]);
                unsigned int B0 = pack_bf16(p[8 * ks1 + 4], p[8 * ks1 + 5]);
                unsigned int B1 = pack_bf16(p[8 * ks1 + 6], p[8 * ks1 + 7]);
                u32x2 r0 = __builtin_amdgcn_permlane32_swap(A0, B0, false, false);
                u32x2 r1 = __builtin_amdgcn_permlane32_swap(A1, B1, false, false);
                union { unsigned int u[4]; s16x8 v; } uu;
                uu.u[0] = r0[0];  // j0,1
                uu.u[1] = r1[0];  // j2,3
                uu.u[2] = r0[1];  // j4,5
                uu.u[3] = r1[1];  // j6,7
                int ks = kt * 2 + ks1;
#pragma unroll
                for (int dt = 0; dt < 2; ++dt) {
                    int d = dt * 32 + l31;
                    int kb = (ks * 2 + l5) ^ (d & 7);
                    s16x8 vf = *(const s16x8*)(&Vs[cur][0] + (size_t)d * 64 + kb * 8);
                    oacc[dt] = __builtin_amdgcn_mfma_f32_32x32x16_bf16(vf, uu.v, oacc[dt], 0, 0, 0);
                }
            }
        }
        rsum += __shfl_xor(rsum, 32);
        lrun += rsum;

        // next tile's 4 loads complete; all waves done reading buf cur
        asm volatile("s_waitcnt vmcnt(0)" ::: "memory");
        __builtin_amdgcn_s_barrier();
    }

    // ---- epilogue: O[s][h*64 + d], d = dt*32 + (r&3) + 8*(r>>2) + 4*l5
    float rl = 1.f / lrun;
    unsigned short* orow = O + ((size_t)qrow * 4 + b) * 1024 + h * 64 + l5 * 4;
#pragma unroll
    for (int dt = 0; dt < 2; ++dt) {
#pragma unroll
        for (int g2 = 0; g2 < 4; ++g2) {
            u32x2 pv;
            pv[0] = pack_bf16(oacc[dt][4 * g2 + 0] * rl, oacc[dt][4 * g2 + 1] * rl);
            pv[1] = pack_bf16(oacc[dt][4 * g2 + 2] * rl, oacc[dt][4 * g2 + 3] * rl);
            *(u32x2*)(orow + dt * 32 + g2 * 8) = pv;
        }
    }
}

// ---------------------------------------------------------------------------
extern "C" void kernel_launch(void* const* d_in, const int* in_sizes, int n_in,
                              void* d_out, int out_size, void* d_ws, size_t ws_size,
                              hipStream_t stream) {
    const void* x    = d_in[0];
    const void* Wqkv = d_in[1];
    const void* bqkv = d_in[2];
    const void* Wout = d_in[3];
    const void* bout = d_in[4];

    char* ws = (char*)d_ws;
    unsigned short* qkv   = (unsigned short*)(ws);              // 48MB
    unsigned short* Obuf  = (unsigned short*)(ws + 50331648);   // 16MB
    unsigned short* WqkvT = (unsigned short*)(ws + 67108864);   // 6MB
    unsigned short* WoutT = (unsigned short*)(ws + 73400320);   // 2MB
    unsigned short* xb    = (unsigned short*)(ws + 75497472);   // 16MB (reused as Vt)
    unsigned short* Vtg   = xb;                                 // alias: xb dead after GEMM1
    float*          bq_f  = (float*)(ws + 92274688);
    float*          bo_f  = (float*)(ws + 92286976);
    int*            flag  = (int*)(ws + 92291072);

    detect_dtype<<<1, 256, 0, stream>>>((const unsigned short*)x, flag);
    convert_x<<<4096, 256, 0, stream>>>(x, xb, flag, 8388608);
    cvt_bias<<<12, 256, 0, stream>>>(bqkv, bq_f, flag, 3072);
    cvt_bias<<<4, 256, 0, stream>>>(bout, bo_f, flag, 1024);
    transpose_cvt<<<dim3(48, 16), 256, 0, stream>>>(Wqkv, WqkvT, flag, 1024, 3072);
    transpose_cvt<<<dim3(16, 16), 256, 0, stream>>>(Wout, WoutT, flag, 1024, 1024);

    // Q prescale = 0.125 * log2(e) -> attention works in exp2 domain
    gemm_pipe_kernel<<<dim3(24, 32), 512, 0, stream>>>(xb, WqkvT, bq_f, qkv,
                                                       8192, 3072, 1024, 1024, 0.18033688f, nullptr);
    transpose_v<<<dim3(32, 64), 256, 0, stream>>>(qkv, Vtg);
    attn_kernel<<<dim3(16, 64), 256, 0, stream>>>(qkv, Vtg, Obuf);
    gemm_pipe_kernel<<<dim3(8, 32), 512, 0, stream>>>(Obuf, WoutT, bo_f, d_out,
                                                      8192, 1024, 1024, 0, 1.0f, flag);
}

// Round 14
// 282.030 us; speedup vs baseline: 1.0454x; 1.0115x over previous
//
#include <hip/hip_runtime.h>

typedef short s16x8 __attribute__((ext_vector_type(8)));
typedef float f32x4 __attribute__((ext_vector_type(4)));
typedef float f32x16 __attribute__((ext_vector_type(16)));
typedef unsigned int u32x2 __attribute__((ext_vector_type(2)));
typedef unsigned int u32x4 __attribute__((ext_vector_type(4)));

__device__ inline float bf2f(unsigned short u) {
    union { float f; unsigned int i; } x; x.i = ((unsigned int)u) << 16; return x.f;
}
__device__ inline unsigned short f2bf(float f) {
    union { float f; unsigned int i; } x; x.f = f;
    unsigned int r = x.i + 0x7fff + ((x.i >> 16) & 1);
    return (unsigned short)(r >> 16);
}
// round-half-up bf16 pair pack via v_perm_b32: low half = a, high half = b
__device__ inline unsigned int pack_bf16(float a, float b) {
    unsigned int ia = __float_as_uint(a) + 0x8000u;
    unsigned int ib = __float_as_uint(b) + 0x8000u;
    return __builtin_amdgcn_perm(ib, ia, 0x07060302u);
}

__device__ inline void gload_lds16(const unsigned short* g, unsigned short* l) {
    __builtin_amdgcn_global_load_lds(
        (const __attribute__((address_space(1))) unsigned int*)g,
        (__attribute__((address_space(3))) unsigned int*)l, 16, 0, 0);
}

// ---------------------------------------------------------------------------
// Input dtype probe: fp32 low-halves have ~uniform exponent bits; bf16 data
// concentrates in [117,129]. flag=1 -> inputs are fp32.
// ---------------------------------------------------------------------------
__global__ void detect_dtype(const unsigned short* __restrict__ x16, int* flag) {
    __shared__ int s[256];
    int tid = threadIdx.x;
    int cnt = 0;
    for (int i = tid; i < 4096; i += 256) {
        unsigned short u = x16[2 * i];
        int e = (u >> 7) & 0xFF;
        if (e >= 117 && e <= 129) cnt++;
    }
    s[tid] = cnt;
    __syncthreads();
    for (int off = 128; off; off >>= 1) {
        if (tid < off) s[tid] += s[tid + off];
        __syncthreads();
    }
    if (tid == 0) *flag = (s[0] < 2048) ? 1 : 0;
}

__global__ void convert_x(const void* __restrict__ in, unsigned short* __restrict__ out,
                          const int* __restrict__ flag, int n) {
    int mode = *flag;
    int i0 = (blockIdx.x * 256 + threadIdx.x) * 8;
    if (i0 >= n) return;
    if (mode) {
        const f32x4* f = (const f32x4*)in;
        f32x4 a = f[i0 >> 2];
        f32x4 c = f[(i0 >> 2) + 1];
        u32x4 o;
        o[0] = pack_bf16(a[0], a[1]);
        o[1] = pack_bf16(a[2], a[3]);
        o[2] = pack_bf16(c[0], c[1]);
        o[3] = pack_bf16(c[2], c[3]);
        *(u32x4*)(out + i0) = o;
    } else {
        *(s16x8*)(out + i0) = *(const s16x8*)((const unsigned short*)in + i0);
    }
}

__global__ void cvt_bias(const void* __restrict__ in, float* __restrict__ out,
                         const int* __restrict__ flag, int n) {
    int i = blockIdx.x * 256 + threadIdx.x;
    if (i >= n) return;
    out[i] = (*flag) ? ((const float*)in)[i] : bf2f(((const unsigned short*)in)[i]);
}

// ---------------------------------------------------------------------------
// Transpose + convert weights: (R x C) fp32/bf16 -> (C x R) bf16
// ---------------------------------------------------------------------------
__global__ void transpose_cvt(const void* __restrict__ in, unsigned short* __restrict__ out,
                              const int* __restrict__ flag, int R, int C) {
    __shared__ unsigned short t[64][72];
    int mode = *flag;
    int r0 = blockIdx.y * 64, c0 = blockIdx.x * 64;
    for (int i = threadIdx.x; i < 64 * 64; i += 256) {
        int r = i >> 6, c = i & 63;
        size_t idx = (size_t)(r0 + r) * C + (c0 + c);
        t[r][c] = mode ? f2bf(((const float*)in)[idx]) : ((const unsigned short*)in)[idx];
    }
    __syncthreads();
    for (int i = threadIdx.x; i < 64 * 64; i += 256) {
        int c = i >> 6, r = i & 63;
        out[(size_t)(c0 + c) * R + (r0 + r)] = t[r][c];
    }
}

// ---------------------------------------------------------------------------
// V transpose: qkv V region -> Vt[bh][64 d][2048 k] (bf16)
// ---------------------------------------------------------------------------
__global__ __launch_bounds__(256) void transpose_v(
    const unsigned short* __restrict__ qkv, unsigned short* __restrict__ Vt) {
    __shared__ unsigned short t[64][72];
    int bh = blockIdx.y; int b = bh >> 4, h = bh & 15;
    int k0 = blockIdx.x * 64;
    int tid = threadIdx.x;
    int kr = tid >> 2, db = (tid & 3) * 16;
    const unsigned short* src = qkv + ((size_t)(k0 + kr) * 4 + b) * 3072 + 2048 + h * 64 + db;
    *(s16x8*)&t[kr][db] = *(const s16x8*)src;
    *(s16x8*)&t[kr][db + 8] = *(const s16x8*)(src + 8);
    __syncthreads();
    int d = tid >> 2, kb = (tid & 3) * 16;
    unsigned short* dst = Vt + (size_t)bh * 131072 + (size_t)d * 2048 + k0 + kb;
    s16x8 a, c;
#pragma unroll
    for (int j = 0; j < 8; ++j) a[j] = t[kb + j][d];
#pragma unroll
    for (int j = 0; j < 8; ++j) c[j] = t[kb + 8 + j][d];
    *(s16x8*)dst = a;
    *(s16x8*)(dst + 8) = c;
}

// ---------------------------------------------------------------------------
// Pipelined GEMM: C = A * BT^T + bias. BM=256, BN=128, BK=64, 512 thr = 8
// waves (4M x 2N). Triple-buffered LDS (144KB), prefetch distance 2,
// counted s_waitcnt vmcnt(6) (never vmcnt(0) mid-loop). XOR LDS layout.
// ---------------------------------------------------------------------------
__global__ __launch_bounds__(512) void gemm_pipe_kernel(
    const unsigned short* __restrict__ A, const unsigned short* __restrict__ BT,
    const float* __restrict__ bias, void* __restrict__ Cout,
    int M, int N, int K, int qcols, float qscale, const int* __restrict__ outf32flag) {
    __shared__ unsigned short As[3][256 * 64];  // 3 x 32KB
    __shared__ unsigned short Bs[3][128 * 64];  // 3 x 16KB
    int tid = threadIdx.x;
    int lane = tid & 63, w = tid >> 6;
    int wr = w >> 1, wc = w & 1;
    int g = lane >> 4, qh = lane & 15;
    int m0 = blockIdx.y * 256, n0 = blockIdx.x * 128;
    int vxor = (lane & 7) ^ (lane >> 3);
    int axor = qh & 7;

    f32x4 z = {0.f, 0.f, 0.f, 0.f};
    f32x4 acc[4][4];
#pragma unroll
    for (int m = 0; m < 4; ++m)
#pragma unroll
        for (int n = 0; n < 4; ++n) acc[m][n] = z;

    const unsigned short* Asrc = A + (size_t)(m0 + w * 8 + (lane >> 3)) * K + vxor * 8;
    const unsigned short* Bsrc = BT + (size_t)(n0 + w * 8 + (lane >> 3)) * K + vxor * 8;

#define STAGE_A(buf, t, j) gload_lds16(Asrc + (size_t)(j) * 64 * K + (size_t)(t) * 64, \
                                       &As[buf][0] + (j) * 4096 + w * 512)
#define STAGE_B(buf, t, j) gload_lds16(Bsrc + (size_t)(j) * 64 * K + (size_t)(t) * 64, \
                                       &Bs[buf][0] + (j) * 4096 + w * 512)

    int NT = K >> 6;
    STAGE_A(0, 0, 0); STAGE_A(0, 0, 1); STAGE_A(0, 0, 2); STAGE_A(0, 0, 3);
    STAGE_B(0, 0, 0); STAGE_B(0, 0, 1);
    STAGE_A(1, 1, 0); STAGE_A(1, 1, 1); STAGE_A(1, 1, 2); STAGE_A(1, 1, 3);
    STAGE_B(1, 1, 0); STAGE_B(1, 1, 1);
    asm volatile("s_waitcnt vmcnt(6)" ::: "memory");
    __builtin_amdgcn_s_barrier();

    int cur = 0;
    for (int t = 0; t < NT; ++t) {
        int nx = cur + 2; if (nx >= 3) nx -= 3;
        bool pf = (t + 2) < NT;
        const unsigned short* Ab = &As[cur][0];
        const unsigned short* Bb = &Bs[cur][0];

        s16x8 bf[4][2];
#pragma unroll
        for (int n = 0; n < 4; ++n)
#pragma unroll
            for (int kk = 0; kk < 2; ++kk)
                bf[n][kk] = *(const s16x8*)(Bb + (size_t)(wc * 64 + n * 16 + qh) * 64 +
                                            (((kk * 4 + g) ^ axor) * 8));

        if (pf) { STAGE_A(nx, t + 2, 0); STAGE_A(nx, t + 2, 1); STAGE_B(nx, t + 2, 0); }
        {
            s16x8 af[2][2];
#pragma unroll
            for (int i = 0; i < 2; ++i)
#pragma unroll
                for (int kk = 0; kk < 2; ++kk)
                    af[i][kk] = *(const s16x8*)(Ab + (size_t)(wr * 64 + i * 16 + qh) * 64 +
                                                (((kk * 4 + g) ^ axor) * 8));
            __builtin_amdgcn_s_setprio(1);
#pragma unroll
            for (int kk = 0; kk < 2; ++kk)
#pragma unroll
                for (int i = 0; i < 2; ++i)
#pragma unroll
                    for (int n = 0; n < 4; ++n)
                        acc[i][n] = __builtin_amdgcn_mfma_f32_16x16x32_bf16(af[i][kk], bf[n][kk], acc[i][n], 0, 0, 0);
            __builtin_amdgcn_s_setprio(0);
        }
        __builtin_amdgcn_s_barrier();

        if (pf) { STAGE_A(nx, t + 2, 2); STAGE_A(nx, t + 2, 3); STAGE_B(nx, t + 2, 1); }
        {
            s16x8 af[2][2];
#pragma unroll
            for (int i = 0; i < 2; ++i)
#pragma unroll
                for (int kk = 0; kk < 2; ++kk)
                    af[i][kk] = *(const s16x8*)(Ab + (size_t)(wr * 64 + (i + 2) * 16 + qh) * 64 +
                                                (((kk * 4 + g) ^ axor) * 8));
            __builtin_amdgcn_s_setprio(1);
#pragma unroll
            for (int kk = 0; kk < 2; ++kk)
#pragma unroll
                for (int i = 0; i < 2; ++i)
#pragma unroll
                    for (int n = 0; n < 4; ++n)
                        acc[i + 2][n] = __builtin_amdgcn_mfma_f32_16x16x32_bf16(af[i][kk], bf[n][kk], acc[i + 2][n], 0, 0, 0);
            __builtin_amdgcn_s_setprio(0);
        }
        if (t + 1 < NT) {
            if (pf) asm volatile("s_waitcnt vmcnt(6)" ::: "memory");
            else    asm volatile("s_waitcnt vmcnt(0)" ::: "memory");
            __builtin_amdgcn_s_barrier();
        }
        cur = cur + 1; if (cur >= 3) cur -= 3;
    }
#undef STAGE_A
#undef STAGE_B

    bool f32out = (outf32flag != nullptr) && (*outf32flag != 0);
    int crow0 = m0 + wr * 64;
    int ccol0 = n0 + wc * 64;
#pragma unroll
    for (int n = 0; n < 4; ++n) {
        int col = ccol0 + n * 16 + qh;
        float bv = bias[col];
        float qs = (col < qcols) ? qscale : 1.0f;
#pragma unroll
        for (int m = 0; m < 4; ++m) {
            int rbase = crow0 + m * 16 + g * 4;
#pragma unroll
            for (int qq = 0; qq < 4; ++qq) {
                float v = (acc[m][n][qq] + bv) * qs;
                if (f32out)
                    ((float*)Cout)[(size_t)(rbase + qq) * N + col] = v;
                else
                    ((unsigned short*)Cout)[(size_t)(rbase + qq) * N + col] = f2bf(v);
            }
        }
    }
}

// ---------------------------------------------------------------------------
// Flash attention, 32x32x16 MFMA, swapped operands, exp2 domain, P fully
// in-register via permlane32_swap (R11-verified structure & layout).
// XCD-aware swizzle: all 16 q-blocks of one (b,h) land on the same XCD
// (default wg->XCD = wg%8 round-robin), so K/V stay in that XCD's L2
// (8 bh x 512KB = 4MB working set per XCD).
// ---------------------------------------------------------------------------
__global__ __launch_bounds__(256) void attn_kernel(
    const unsigned short* __restrict__ qkv, const unsigned short* __restrict__ Vt,
    unsigned short* __restrict__ O) {
    int L = blockIdx.y * 16 + blockIdx.x;   // 0..1023
    int xcd = L & 7;
    int i = L >> 3;                          // 0..127
    int bh = xcd * 8 + (i & 7);
    int q0 = (i >> 3) << 7;                  // (i>>3) * 128
    int b = bh >> 4, h = bh & 15;
    int tid = threadIdx.x, lane = tid & 63, w = tid >> 6;
    int l31 = lane & 31, l5 = lane >> 5;

    __shared__ unsigned short Ks[8 * 64 * 8];   // [gd=d/8][k][8]  8KB
    __shared__ unsigned short Vs[64 * 64];      // [d][kb^(d&7)]   8KB

    // Q B-frags: step st: k-chunk d = st*16 + l5*8 + j; col = q0 + w*32 + l31
    int qrow = q0 + w * 32 + l31;
    const unsigned short* qp = qkv + ((size_t)qrow * 4 + b) * 3072 + h * 64 + l5 * 8;
    s16x8 qf[4];
#pragma unroll
    for (int st = 0; st < 4; ++st) qf[st] = *(const s16x8*)(qp + st * 16);

    f32x16 z16 = {0.f,0.f,0.f,0.f,0.f,0.f,0.f,0.f,0.f,0.f,0.f,0.f,0.f,0.f,0.f,0.f};
    f32x16 oacc[2];
    oacc[0] = z16; oacc[1] = z16;
    float lrun = 0.f;

    int vxor = (lane & 7) ^ (lane >> 3);

    // hoisted staging pointers (advance per tile, no per-tile recompute)
    const unsigned short* kptr = qkv + ((size_t)lane * 4 + b) * 3072 + 1024 + h * 64;
    const unsigned short* vp0 = Vt + (size_t)bh * 131072 +
                                (size_t)((0 * 4 + w) * 8 + (lane >> 3)) * 2048 + vxor * 8;
    const unsigned short* vp1 = Vt + (size_t)bh * 131072 +
                                (size_t)((1 * 4 + w) * 8 + (lane >> 3)) * 2048 + vxor * 8;

    for (int t = 0; t < 32; ++t) {
        __syncthreads();
        // stage K tile: Ks[gd][k][e] = K[k0+k][gd*8+e]
        gload_lds16(kptr + w * 8, Ks + (size_t)w * 512);
        gload_lds16(kptr + (w + 4) * 8, Ks + (size_t)(w + 4) * 512);
        // stage V^T tile, inverse-swizzled source, linear LDS dest:
        // Vs[d][blk][j] = V^T[d][k0 + (blk^(d&7))*8 + j]
        gload_lds16(vp0, Vs + (size_t)w * 512);
        gload_lds16(vp1, Vs + (size_t)(4 + w) * 512);
        kptr += 786432;  // 64 rows * 12288
        vp0 += 64;
        vp1 += 64;
        __syncthreads();

        // ---- S^T[k][q] (log2 domain): sc[kt], k = kt*32 + (r&3)+8*(r>>2)+4*l5
        f32x16 sc[2];
        sc[0] = z16; sc[1] = z16;
#pragma unroll
        for (int st = 0; st < 4; ++st) {
            int gd = st * 2 + l5;
#pragma unroll
            for (int kt = 0; kt < 2; ++kt) {
                s16x8 kf = *(const s16x8*)(Ks + ((size_t)(gd * 64 + kt * 32 + l31)) * 8);
                sc[kt] = __builtin_amdgcn_mfma_f32_32x32x16_bf16(kf, qf[st], sc[kt], 0, 0, 0);
            }
        }

        // ---- P = exp2(S) raw; PV B-frags in-register; PV accumulate
        float rsum = 0.f;
#pragma unroll
        for (int kt = 0; kt < 2; ++kt) {
            float p[16];
#pragma unroll
            for (int r = 0; r < 16; ++r) {
                p[r] = __builtin_amdgcn_exp2f(sc[kt][r]);
                rsum += p[r];
            }
#pragma unroll
            for (int ks1 = 0; ks1 < 2; ++ks1) {
                unsigned int A0 = pack_bf16(p[8 * ks1 + 0], p[8 * ks1 + 1]);
                unsigned int A1 = pack_bf16(p[8 * ks1 + 2], p[8 * ks1 + 3]);
                unsigned int B0 = pack_bf16(p[8 * ks1 + 4], p[8 * ks1 + 5]);
                unsigned int B1 = pack_bf16(p[8 * ks1 + 6], p[8 * ks1 + 7]);
                u32x2 r0 = __builtin_amdgcn_permlane32_swap(A0, B0, false, false);
                u32x2 r1 = __builtin_amdgcn_permlane32_swap(A1, B1, false, false);
                union { unsigned int u[4]; s16x8 v; } uu;
                uu.u[0] = r0[0];  // j0,1
                uu.u[1] = r1[0];  // j2,3
                uu.u[2] = r0[1];  // j4,5
                uu.u[3] = r1[1];  // j6,7
                int ks = kt * 2 + ks1;
#pragma unroll
                for (int dt = 0; dt < 2; ++dt) {
                    int d = dt * 32 + l31;
                    int kb = (ks * 2 + l5) ^ (d & 7);
                    s16x8 vf = *(const s16x8*)(Vs + (size_t)d * 64 + kb * 8);
                    oacc[dt] = __builtin_amdgcn_mfma_f32_32x32x16_bf16(vf, uu.v, oacc[dt], 0, 0, 0);
                }
            }
        }
        rsum += __shfl_xor(rsum, 32);
        lrun += rsum;
    }

    // ---- epilogue: O[s][h*64 + d], d = dt*32 + (r&3) + 8*(r>>2) + 4*l5
    float rl = 1.f / lrun;
    unsigned short* orow = O + ((size_t)qrow * 4 + b) * 1024 + h * 64 + l5 * 4;
#pragma unroll
    for (int dt = 0; dt < 2; ++dt) {
#pragma unroll
        for (int g2 = 0; g2 < 4; ++g2) {
            u32x2 pv;
            pv[0] = pack_bf16(oacc[dt][4 * g2 + 0] * rl, oacc[dt][4 * g2 + 1] * rl);
            pv[1] = pack_bf16(oacc[dt][4 * g2 + 2] * rl, oacc[dt][4 * g2 + 3] * rl);
            *(u32x2*)(orow + dt * 32 + g2 * 8) = pv;
        }
    }
}

// ---------------------------------------------------------------------------
extern "C" void kernel_launch(void* const* d_in, const int* in_sizes, int n_in,
                              void* d_out, int out_size, void* d_ws, size_t ws_size,
                              hipStream_t stream) {
    const void* x    = d_in[0];
    const void* Wqkv = d_in[1];
    const void* bqkv = d_in[2];
    const void* Wout = d_in[3];
    const void* bout = d_in[4];

    char* ws = (char*)d_ws;
    unsigned short* qkv   = (unsigned short*)(ws);              // 48MB
    unsigned short* Obuf  = (unsigned short*)(ws + 50331648);   // 16MB
    unsigned short* WqkvT = (unsigned short*)(ws + 67108864);   // 6MB
    unsigned short* WoutT = (unsigned short*)(ws + 73400320);   // 2MB
    unsigned short* xb    = (unsigned short*)(ws + 75497472);   // 16MB (reused as Vt)
    unsigned short* Vtg   = xb;                                 // alias: xb dead after GEMM1
    float*          bq_f  = (float*)(ws + 92274688);
    float*          bo_f  = (float*)(ws + 92286976);
    int*            flag  = (int*)(ws + 92291072);

    detect_dtype<<<1, 256, 0, stream>>>((const unsigned short*)x, flag);
    convert_x<<<4096, 256, 0, stream>>>(x, xb, flag, 8388608);
    cvt_bias<<<12, 256, 0, stream>>>(bqkv, bq_f, flag, 3072);
    cvt_bias<<<4, 256, 0, stream>>>(bout, bo_f, flag, 1024);
    transpose_cvt<<<dim3(48, 16), 256, 0, stream>>>(Wqkv, WqkvT, flag, 1024, 3072);
    transpose_cvt<<<dim3(16, 16), 256, 0, stream>>>(Wout, WoutT, flag, 1024, 1024);

    // Q prescale = 0.125 * log2(e) -> attention works in exp2 domain
    gemm_pipe_kernel<<<dim3(24, 32), 512, 0, stream>>>(xb, WqkvT, bq_f, qkv,
                                                       8192, 3072, 1024, 1024, 0.18033688f, nullptr);
    transpose_v<<<dim3(32, 64), 256, 0, stream>>>(qkv, Vtg);
    attn_kernel<<<dim3(16, 64), 256, 0, stream>>>(qkv, Vtg, Obuf);
    gemm_pipe_kernel<<<dim3(8, 32), 512, 0, stream>>>(Obuf, WoutT, bo_f, d_out,
                                                      8192, 1024, 1024, 0, 1.0f, flag);
}